// Round 8
// baseline (185.643 us; speedup 1.0000x reference)
//
#include <hip/hip_runtime.h>
#include <math.h>

typedef _Float16 f16_t;
typedef __attribute__((ext_vector_type(8))) _Float16 f16x8;
typedef __attribute__((ext_vector_type(4))) float f32x4;

#define NTOK 131072
#define MT   128      // tokens per block
#define TPB  256      // 4 waves; each wave owns 32 tokens end-to-end; ZERO barriers
#define RP16 72       // relay pitch (f16): 144 B/row, 16B-aligned frags, 2-way banks
#define OP32 68       // out-stage pitch (f32): 272 B/row, 16B-aligned, ~2-way banks
#define SLABB 8704    // per-wave slab bytes = max(32*72*2, 32*68*4)

// ws layout (f16 elems), produced by prep_w; stays L2-hot (96 KB total)
#define OFF_KEY 0
#define OFF_VAL 4096
#define OFF_T   8192
#define OFF_D1  40960
#define OFF_D2  45056
#define OFF_D3  47104
#define WTOT    49152

__device__ __forceinline__ f32x4 mfma1(f16x8 a, f16x8 b, f32x4 c) {
    return __builtin_amdgcn_mfma_f32_16x16x32_f16(a, b, c, 0, 0, 0);
}

struct Bfrag { f16x8 h0, h1; };
__device__ __forceinline__ Bfrag loadB(const f16_t* __restrict__ b, int off) {
    Bfrag r;
    r.h0 = *(const f16x8*)(b + off);
    r.h1 = *(const f16x8*)(b + off + 32);
    return r;
}

// K=64 GEMM (B from global/L2), single row-tile
template<int NC>
__device__ __forceinline__ void gemm1rt(const f16_t* __restrict__ bw,
                                        int l15, int quad,
                                        const f16x8 ah[2], f32x4 acc[NC])
{
#pragma unroll
    for (int c = 0; c < NC; ++c) {
        Bfrag b = loadB(bw, (16 * c + l15) * 64 + quad * 8);
        acc[c] = mfma1(ah[1], b.h1, mfma1(ah[0], b.h0, acc[c]));
    }
}
// K=64 GEMM, B shared across both row-tiles
template<int NC>
__device__ __forceinline__ void gemm2rt(const f16_t* __restrict__ bw,
                                        int l15, int quad,
                                        const f16x8 ah[2][2], f32x4 acc[2][NC])
{
#pragma unroll
    for (int c = 0; c < NC; ++c) {
        Bfrag b = loadB(bw, (16 * c + l15) * 64 + quad * 8);
#pragma unroll
        for (int rt = 0; rt < 2; ++rt)
            acc[rt][c] = mfma1(ah[rt][1], b.h1, mfma1(ah[rt][0], b.h0, acc[rt][c]));
    }
}

// ---------------- prep: transpose all weights into ws as fp16 --------------
__global__ __launch_bounds__(256)
void prep_w(const float* __restrict__ keyW, const float* __restrict__ valW,
            const float* __restrict__ TW,   const float* __restrict__ TB,
            const float* __restrict__ d1W,  const float* __restrict__ d2W,
            const float* __restrict__ d3W,  f16_t* __restrict__ wsf)
{
    int idx = blockIdx.x * 256 + threadIdx.x;
    if (idx >= WTOT) return;
    float src;
    if (idx < OFF_VAL) {
        int r = idx - OFF_KEY, n = r >> 6, j = r & 63;
        src = keyW[j * 64 + n];
    } else if (idx < OFF_T) {
        int r = idx - OFF_VAL, n = r >> 6, j = r & 63;
        src = valW[j * 64 + n];
    } else if (idx < OFF_D1) {
        int r = idx - OFF_T, p = r >> 12, q = r & 4095;
        src = (p < 7) ? TW[p * 4096 + q] : TB[q];
    } else if (idx < OFF_D2) {
        int r = idx - OFF_D1, n = r >> 6, j = r & 63;
        src = d1W[j * 64 + n];
    } else if (idx < OFF_D3) {
        int r = idx - OFF_D2, n = r >> 6, j = r & 63;
        src = d2W[j * 32 + n];
    } else {
        int r = idx - OFF_D3, n = r >> 5, j = r & 31;
        src = d3W[j * 64 + n];
    }
    wsf[idx] = (f16_t)src;
}

// ------- main: 4 waves/block, 4 blocks/CU, zero barriers, full-line stores -
__global__ __launch_bounds__(TPB, 4)
void fused_mfma(const float* __restrict__ kv_in, const float* __restrict__ q_in,
                const float* __restrict__ keyB,  const float* __restrict__ valB,
                const float* __restrict__ d1B,   const float* __restrict__ d2B,
                const float* __restrict__ d3B,   const float* __restrict__ scale_p,
                const f16_t* __restrict__ wsf,   float* __restrict__ out)
{
    // per-wave slab: lives as f16 relay (kv staging, x/h relays), then reused
    // as f32 out-stage for the full-line store epilogue. Wave-private.
    __shared__ __align__(16) unsigned char Slab[4][SLABB];   // 34816 B
    __shared__ __align__(16) float Qs[8][MT];                // 4096 B -> 38912 total

    const int tid  = threadIdx.x;
    const int wv   = tid >> 6, lane = tid & 63;
    const int quad = lane >> 4, l15 = lane & 15;
    const int RB   = wv * 32;
    const long t0  = (long)blockIdx.x * MT;

    f16_t* __restrict__ Rf = (f16_t*)Slab[wv];
    float* __restrict__ Of = (float*)Slab[wv];

    // ---- coalesced kv staging -> fp16 relay (wave-private) ----
    {
        const int r = lane >> 1, half = lane & 1;
        const float4* p4 = (const float4*)(kv_in + (t0 + RB + r) * 64 + half * 32);
        f16_t* dst = Rf + r * RP16 + half * 32;
#pragma unroll
        for (int b = 0; b < 4; ++b) {
            float4 f0 = p4[2 * b], f1 = p4[2 * b + 1];
            f16x8 h;
            h[0] = (f16_t)f0.x; h[1] = (f16_t)f0.y; h[2] = (f16_t)f0.z; h[3] = (f16_t)f0.w;
            h[4] = (f16_t)f1.x; h[5] = (f16_t)f1.y; h[6] = (f16_t)f1.z; h[7] = (f16_t)f1.w;
            *(f16x8*)(dst + 8 * b) = h;
        }
    }
    // ---- q' -> Qs (wave-private cols) ----
    if (lane < 32) {
        const float* qp = q_in + (t0 + RB + lane) * 7;
#pragma unroll
        for (int p = 0; p < 7; ++p) Qs[p][RB + lane] = qp[p];
        Qs[7][RB + lane] = 1.0f;
    }

    float kb[4], vb[4];
#pragma unroll
    for (int c = 0; c < 4; ++c) { kb[c] = keyB[16 * c + l15]; vb[c] = valB[16 * c + l15]; }
    const float sc = scale_p[0];

    // ---- A-fragments (kv) for both row-tiles ----
    f16x8 ah[2][2];
#pragma unroll
    for (int rt = 0; rt < 2; ++rt)
#pragma unroll
        for (int ks = 0; ks < 2; ++ks)
            ah[rt][ks] = *(const f16x8*)(Rf + (16 * rt + l15) * RP16 + ks * 32 + quad * 8);

    // ---- T stage (2rt): q = sum_p q'_p * (KV @ T_p^T) ----
    f32x4 qacc[2][4] = {};
#pragma unroll 2
    for (int p = 0; p < 8; ++p) {
        f32x4 tmp[2][4] = {};
        gemm2rt<4>(wsf + OFF_T + p * 4096, l15, quad, ah, tmp);
        f32x4 qp0 = *(const f32x4*)&Qs[p][RB + quad * 4];
        f32x4 qp1 = *(const f32x4*)&Qs[p][RB + 16 + quad * 4];
#pragma unroll
        for (int c = 0; c < 4; ++c)
#pragma unroll
            for (int e = 0; e < 4; ++e) {
                qacc[0][c][e] = fmaf(qp0[e], tmp[0][c][e], qacc[0][c][e]);
                qacc[1][c][e] = fmaf(qp1[e], tmp[1][c][e], qacc[1][c][e]);
            }
    }

    // ---- per row-tile: combined k|v GEMM + elementwise + x relay ----
#pragma unroll 1
    for (int rt = 0; rt < 2; ++rt) {
        f32x4 kv8[8] = {};
        gemm1rt<8>(wsf + OFF_KEY, l15, quad, ah[rt], kv8);

        f32x4 sv[4], mx;
#pragma unroll
        for (int e = 0; e < 4; ++e) mx[e] = -3.4e38f;
#pragma unroll
        for (int c = 0; c < 4; ++c) {
            sv[c] = (kv8[4 + c] + vb[c]) * sc;
#pragma unroll
            for (int e = 0; e < 4; ++e) mx[e] = fmaxf(mx[e], sv[c][e]);
        }
#pragma unroll
        for (int m = 1; m < 16; m <<= 1)
#pragma unroll
            for (int e = 0; e < 4; ++e) mx[e] = fmaxf(mx[e], __shfl_xor(mx[e], m, 64));
        f32x4 se = {};
#pragma unroll
        for (int c = 0; c < 4; ++c) {
#pragma unroll
            for (int e = 0; e < 4; ++e) sv[c][e] = __expf(sv[c][e] - mx[e]);
            se += sv[c];
        }
#pragma unroll
        for (int m = 1; m < 16; m <<= 1)
#pragma unroll
            for (int e = 0; e < 4; ++e) se[e] += __shfl_xor(se[e], m, 64);
        f32x4 nr = {};
        f32x4 at[4];
#pragma unroll
        for (int c = 0; c < 4; ++c) {
            at[c] = qacc[rt][c] * (kv8[c] + kb[c]);
            nr += at[c] * at[c];
        }
#pragma unroll
        for (int m = 1; m < 16; m <<= 1)
#pragma unroll
            for (int e = 0; e < 4; ++e) nr[e] += __shfl_xor(nr[e], m, 64);
        f32x4 fac;
#pragma unroll
        for (int e = 0; e < 4; ++e)
            fac[e] = 1.0f / (fmaxf(sqrtf(nr[e]), 1e-8f) * se[e]);
#pragma unroll
        for (int c = 0; c < 4; ++c)
#pragma unroll
            for (int e = 0; e < 4; ++e)
                Rf[(16 * rt + quad * 4 + e) * RP16 + 16 * c + l15] =
                    (f16_t)(at[c][e] * sv[c][e] * fac[e]);
    }

    // ---- d1: h1 = relu(x @ d1 + b1) ----
    f16x8 xh[2][2];
#pragma unroll
    for (int rt = 0; rt < 2; ++rt)
#pragma unroll
        for (int ks = 0; ks < 2; ++ks)
            xh[rt][ks] = *(const f16x8*)(Rf + (16 * rt + l15) * RP16 + ks * 32 + quad * 8);
    f32x4 h1a[2][4] = {};
    gemm2rt<4>(wsf + OFF_D1, l15, quad, xh, h1a);
    {
        float b1[4];
#pragma unroll
        for (int c = 0; c < 4; ++c) b1[c] = d1B[16 * c + l15];
#pragma unroll
        for (int rt = 0; rt < 2; ++rt)
#pragma unroll
            for (int c = 0; c < 4; ++c)
#pragma unroll
                for (int e = 0; e < 4; ++e)
                    Rf[(16 * rt + quad * 4 + e) * RP16 + 16 * c + l15] =
                        (f16_t)fmaxf(h1a[rt][c][e] + b1[c], 0.f);
    }

    // ---- d2: h2 = relu(h1 @ d2 + b2), 32 cols ----
#pragma unroll
    for (int rt = 0; rt < 2; ++rt)
#pragma unroll
        for (int ks = 0; ks < 2; ++ks)
            xh[rt][ks] = *(const f16x8*)(Rf + (16 * rt + l15) * RP16 + ks * 32 + quad * 8);
    f32x4 h2a[2][2] = {};
    gemm2rt<2>(wsf + OFF_D2, l15, quad, xh, h2a);
    {
        float b2[2];
#pragma unroll
        for (int c = 0; c < 2; ++c) b2[c] = d2B[16 * c + l15];
#pragma unroll
        for (int rt = 0; rt < 2; ++rt)
#pragma unroll
            for (int c = 0; c < 2; ++c)
#pragma unroll
                for (int e = 0; e < 4; ++e)
                    Rf[(16 * rt + quad * 4 + e) * RP16 + 16 * c + l15] =
                        (f16_t)fmaxf(h2a[rt][c][e] + b2[c], 0.f);
    }

    // ---- d3: out = h2 @ d3 + b3 (K=32) -> f32 out-stage in slab ----
    f16x8 a3[2];
#pragma unroll
    for (int rt = 0; rt < 2; ++rt)
        a3[rt] = *(const f16x8*)(Rf + (16 * rt + l15) * RP16 + quad * 8);
    float b3[4];
#pragma unroll
    for (int c = 0; c < 4; ++c) b3[c] = d3B[16 * c + l15];
#pragma unroll
    for (int c = 0; c < 4; ++c) {
        f16x8 bw = *(const f16x8*)(wsf + OFF_D3 + (16 * c + l15) * 32 + quad * 8);
#pragma unroll
        for (int rt = 0; rt < 2; ++rt) {
            f32x4 a = {};
            a = mfma1(a3[rt], bw, a);
#pragma unroll
            for (int e = 0; e < 4; ++e)
                Of[(16 * rt + quad * 4 + e) * OP32 + 16 * c + l15] = a[e] + b3[c];
        }
    }

    // ---- full-line store epilogue: 8 x 1KB contiguous wave-stores ----
    float* __restrict__ obase = out + (t0 + RB) * 64;
#pragma unroll
    for (int i = 0; i < 8; ++i) {
        const int r4 = i * 4 + (lane >> 4);
        f32x4 v = *(const f32x4*)(Of + r4 * OP32 + (lane & 15) * 4);
        *(f32x4*)(obase + i * 256 + lane * 4) = v;
    }
}

extern "C" void kernel_launch(void* const* d_in, const int* in_sizes, int n_in,
                              void* d_out, int out_size, void* d_ws, size_t ws_size,
                              hipStream_t stream) {
    (void)in_sizes; (void)n_in; (void)out_size; (void)ws_size;
    const float* kv_in = (const float*)d_in[0];
    const float* q_in  = (const float*)d_in[1];
    const float* keyW  = (const float*)d_in[2];
    const float* keyB  = (const float*)d_in[3];
    const float* valW  = (const float*)d_in[4];
    const float* valB  = (const float*)d_in[5];
    const float* TW    = (const float*)d_in[6];
    const float* TB    = (const float*)d_in[7];
    const float* d1W   = (const float*)d_in[8];
    const float* d1B   = (const float*)d_in[9];
    const float* d2W   = (const float*)d_in[10];
    const float* d2B   = (const float*)d_in[11];
    const float* d3W   = (const float*)d_in[12];
    const float* d3B   = (const float*)d_in[13];
    const float* scale = (const float*)d_in[14];
    f16_t* wsf = (f16_t*)d_ws;
    float* outp = (float*)d_out;

    prep_w<<<(WTOT + 255) / 256, 256, 0, stream>>>(keyW, valW, TW, TB, d1W, d2W, d3W, wsf);
    fused_mfma<<<NTOK / MT, TPB, 0, stream>>>(kv_in, q_in, keyB, valB,
                                              d1B, d2B, d3B, scale, wsf, outp);
}

// Round 9
// 173.220 us; speedup vs baseline: 1.0717x; 1.0717x over previous
//
#include <hip/hip_runtime.h>
#include <math.h>

typedef _Float16 f16_t;
typedef __attribute__((ext_vector_type(8))) _Float16 f16x8;
typedef __attribute__((ext_vector_type(4))) float f32x4;

#define NTOK 131072
#define MT   128      // tokens per block
#define TPB  256      // 4 waves; each wave owns 32 tokens end-to-end; ZERO barriers
#define RP16 72       // relay pitch (f16): 144 B/row, 16B-aligned frags, 2-way banks
#define OP32 68       // out-stage pitch (f32): 272 B/row, 16B-aligned, ~2-way banks
#define SLABB 8704    // per-wave slab bytes = max(32*72*2, 32*68*4)

// ws layout (f16 elems), produced by prep_w; stays L2-hot (96 KB total)
#define OFF_KEY 0
#define OFF_VAL 4096
#define OFF_T   8192
#define OFF_D1  40960
#define OFF_D2  45056
#define OFF_D3  47104
#define WTOT    49152

__device__ __forceinline__ f32x4 mfma1(f16x8 a, f16x8 b, f32x4 c) {
    return __builtin_amdgcn_mfma_f32_16x16x32_f16(a, b, c, 0, 0, 0);
}

struct Bfrag { f16x8 h0, h1; };
__device__ __forceinline__ Bfrag loadB(const f16_t* __restrict__ b, int off) {
    Bfrag r;
    r.h0 = *(const f16x8*)(b + off);
    r.h1 = *(const f16x8*)(b + off + 32);
    return r;
}

// K=64 GEMM (B from global/L2), single row-tile
template<int NC>
__device__ __forceinline__ void gemm1rt(const f16_t* __restrict__ bw,
                                        int l15, int quad,
                                        const f16x8 ah[2], f32x4 acc[NC])
{
#pragma unroll
    for (int c = 0; c < NC; ++c) {
        Bfrag b = loadB(bw, (16 * c + l15) * 64 + quad * 8);
        acc[c] = mfma1(ah[1], b.h1, mfma1(ah[0], b.h0, acc[c]));
    }
}
// K=64 GEMM, B shared across both row-tiles
template<int NC>
__device__ __forceinline__ void gemm2rt(const f16_t* __restrict__ bw,
                                        int l15, int quad,
                                        const f16x8 ah[2][2], f32x4 acc[2][NC])
{
#pragma unroll
    for (int c = 0; c < NC; ++c) {
        Bfrag b = loadB(bw, (16 * c + l15) * 64 + quad * 8);
#pragma unroll
        for (int rt = 0; rt < 2; ++rt)
            acc[rt][c] = mfma1(ah[rt][1], b.h1, mfma1(ah[rt][0], b.h0, acc[rt][c]));
    }
}

// ---------------- prep: transpose all weights into ws as fp16 --------------
__global__ __launch_bounds__(256)
void prep_w(const float* __restrict__ keyW, const float* __restrict__ valW,
            const float* __restrict__ TW,   const float* __restrict__ TB,
            const float* __restrict__ d1W,  const float* __restrict__ d2W,
            const float* __restrict__ d3W,  f16_t* __restrict__ wsf)
{
    int idx = blockIdx.x * 256 + threadIdx.x;
    if (idx >= WTOT) return;
    float src;
    if (idx < OFF_VAL) {
        int r = idx - OFF_KEY, n = r >> 6, j = r & 63;
        src = keyW[j * 64 + n];
    } else if (idx < OFF_T) {
        int r = idx - OFF_VAL, n = r >> 6, j = r & 63;
        src = valW[j * 64 + n];
    } else if (idx < OFF_D1) {
        int r = idx - OFF_T, p = r >> 12, q = r & 4095;
        src = (p < 7) ? TW[p * 4096 + q] : TB[q];
    } else if (idx < OFF_D2) {
        int r = idx - OFF_D1, n = r >> 6, j = r & 63;
        src = d1W[j * 64 + n];
    } else if (idx < OFF_D3) {
        int r = idx - OFF_D2, n = r >> 6, j = r & 63;
        src = d2W[j * 32 + n];
    } else {
        int r = idx - OFF_D3, n = r >> 5, j = r & 31;
        src = d3W[j * 64 + n];
    }
    wsf[idx] = (f16_t)src;
}

// ------- main: R8 structure, but register budget 256 (launch_bounds ,2) ----
// R9 experiment: ONLY change vs R8 is __launch_bounds__(TPB, 4) -> (TPB, 2).
// Hypothesis: the (,4) 128-reg budget forced scratch spills; spill stores are
// the ~130 MB WRITE excess seen in R4/R5/R6/R8.
__global__ __launch_bounds__(TPB, 2)
void fused_mfma(const float* __restrict__ kv_in, const float* __restrict__ q_in,
                const float* __restrict__ keyB,  const float* __restrict__ valB,
                const float* __restrict__ d1B,   const float* __restrict__ d2B,
                const float* __restrict__ d3B,   const float* __restrict__ scale_p,
                const f16_t* __restrict__ wsf,   float* __restrict__ out)
{
    // per-wave slab: lives as f16 relay (kv staging, x/h relays), then reused
    // as f32 out-stage for the full-line store epilogue. Wave-private.
    __shared__ __align__(16) unsigned char Slab[4][SLABB];   // 34816 B
    __shared__ __align__(16) float Qs[8][MT];                // 4096 B -> 38912 total

    const int tid  = threadIdx.x;
    const int wv   = tid >> 6, lane = tid & 63;
    const int quad = lane >> 4, l15 = lane & 15;
    const int RB   = wv * 32;
    const long t0  = (long)blockIdx.x * MT;

    f16_t* __restrict__ Rf = (f16_t*)Slab[wv];
    float* __restrict__ Of = (float*)Slab[wv];

    // ---- coalesced kv staging -> fp16 relay (wave-private) ----
    {
        const int r = lane >> 1, half = lane & 1;
        const float4* p4 = (const float4*)(kv_in + (t0 + RB + r) * 64 + half * 32);
        f16_t* dst = Rf + r * RP16 + half * 32;
#pragma unroll
        for (int b = 0; b < 4; ++b) {
            float4 f0 = p4[2 * b], f1 = p4[2 * b + 1];
            f16x8 h;
            h[0] = (f16_t)f0.x; h[1] = (f16_t)f0.y; h[2] = (f16_t)f0.z; h[3] = (f16_t)f0.w;
            h[4] = (f16_t)f1.x; h[5] = (f16_t)f1.y; h[6] = (f16_t)f1.z; h[7] = (f16_t)f1.w;
            *(f16x8*)(dst + 8 * b) = h;
        }
    }
    // ---- q' -> Qs (wave-private cols) ----
    if (lane < 32) {
        const float* qp = q_in + (t0 + RB + lane) * 7;
#pragma unroll
        for (int p = 0; p < 7; ++p) Qs[p][RB + lane] = qp[p];
        Qs[7][RB + lane] = 1.0f;
    }

    float kb[4], vb[4];
#pragma unroll
    for (int c = 0; c < 4; ++c) { kb[c] = keyB[16 * c + l15]; vb[c] = valB[16 * c + l15]; }
    const float sc = scale_p[0];

    // ---- A-fragments (kv) for both row-tiles ----
    f16x8 ah[2][2];
#pragma unroll
    for (int rt = 0; rt < 2; ++rt)
#pragma unroll
        for (int ks = 0; ks < 2; ++ks)
            ah[rt][ks] = *(const f16x8*)(Rf + (16 * rt + l15) * RP16 + ks * 32 + quad * 8);

    // ---- T stage (2rt): q = sum_p q'_p * (KV @ T_p^T) ----
    f32x4 qacc[2][4] = {};
#pragma unroll 2
    for (int p = 0; p < 8; ++p) {
        f32x4 tmp[2][4] = {};
        gemm2rt<4>(wsf + OFF_T + p * 4096, l15, quad, ah, tmp);
        f32x4 qp0 = *(const f32x4*)&Qs[p][RB + quad * 4];
        f32x4 qp1 = *(const f32x4*)&Qs[p][RB + 16 + quad * 4];
#pragma unroll
        for (int c = 0; c < 4; ++c)
#pragma unroll
            for (int e = 0; e < 4; ++e) {
                qacc[0][c][e] = fmaf(qp0[e], tmp[0][c][e], qacc[0][c][e]);
                qacc[1][c][e] = fmaf(qp1[e], tmp[1][c][e], qacc[1][c][e]);
            }
    }

    // ---- per row-tile: combined k|v GEMM + elementwise + x relay ----
#pragma unroll 1
    for (int rt = 0; rt < 2; ++rt) {
        f32x4 kv8[8] = {};
        gemm1rt<8>(wsf + OFF_KEY, l15, quad, ah[rt], kv8);

        f32x4 sv[4], mx;
#pragma unroll
        for (int e = 0; e < 4; ++e) mx[e] = -3.4e38f;
#pragma unroll
        for (int c = 0; c < 4; ++c) {
            sv[c] = (kv8[4 + c] + vb[c]) * sc;
#pragma unroll
            for (int e = 0; e < 4; ++e) mx[e] = fmaxf(mx[e], sv[c][e]);
        }
#pragma unroll
        for (int m = 1; m < 16; m <<= 1)
#pragma unroll
            for (int e = 0; e < 4; ++e) mx[e] = fmaxf(mx[e], __shfl_xor(mx[e], m, 64));
        f32x4 se = {};
#pragma unroll
        for (int c = 0; c < 4; ++c) {
#pragma unroll
            for (int e = 0; e < 4; ++e) sv[c][e] = __expf(sv[c][e] - mx[e]);
            se += sv[c];
        }
#pragma unroll
        for (int m = 1; m < 16; m <<= 1)
#pragma unroll
            for (int e = 0; e < 4; ++e) se[e] += __shfl_xor(se[e], m, 64);
        f32x4 nr = {};
        f32x4 at[4];
#pragma unroll
        for (int c = 0; c < 4; ++c) {
            at[c] = qacc[rt][c] * (kv8[c] + kb[c]);
            nr += at[c] * at[c];
        }
#pragma unroll
        for (int m = 1; m < 16; m <<= 1)
#pragma unroll
            for (int e = 0; e < 4; ++e) nr[e] += __shfl_xor(nr[e], m, 64);
        f32x4 fac;
#pragma unroll
        for (int e = 0; e < 4; ++e)
            fac[e] = 1.0f / (fmaxf(sqrtf(nr[e]), 1e-8f) * se[e]);
#pragma unroll
        for (int c = 0; c < 4; ++c)
#pragma unroll
            for (int e = 0; e < 4; ++e)
                Rf[(16 * rt + quad * 4 + e) * RP16 + 16 * c + l15] =
                    (f16_t)(at[c][e] * sv[c][e] * fac[e]);
    }

    // ---- d1: h1 = relu(x @ d1 + b1) ----
    f16x8 xh[2][2];
#pragma unroll
    for (int rt = 0; rt < 2; ++rt)
#pragma unroll
        for (int ks = 0; ks < 2; ++ks)
            xh[rt][ks] = *(const f16x8*)(Rf + (16 * rt + l15) * RP16 + ks * 32 + quad * 8);
    f32x4 h1a[2][4] = {};
    gemm2rt<4>(wsf + OFF_D1, l15, quad, xh, h1a);
    {
        float b1[4];
#pragma unroll
        for (int c = 0; c < 4; ++c) b1[c] = d1B[16 * c + l15];
#pragma unroll
        for (int rt = 0; rt < 2; ++rt)
#pragma unroll
            for (int c = 0; c < 4; ++c)
#pragma unroll
                for (int e = 0; e < 4; ++e)
                    Rf[(16 * rt + quad * 4 + e) * RP16 + 16 * c + l15] =
                        (f16_t)fmaxf(h1a[rt][c][e] + b1[c], 0.f);
    }

    // ---- d2: h2 = relu(h1 @ d2 + b2), 32 cols ----
#pragma unroll
    for (int rt = 0; rt < 2; ++rt)
#pragma unroll
        for (int ks = 0; ks < 2; ++ks)
            xh[rt][ks] = *(const f16x8*)(Rf + (16 * rt + l15) * RP16 + ks * 32 + quad * 8);
    f32x4 h2a[2][2] = {};
    gemm2rt<2>(wsf + OFF_D2, l15, quad, xh, h2a);
    {
        float b2[2];
#pragma unroll
        for (int c = 0; c < 2; ++c) b2[c] = d2B[16 * c + l15];
#pragma unroll
        for (int rt = 0; rt < 2; ++rt)
#pragma unroll
            for (int c = 0; c < 2; ++c)
#pragma unroll
                for (int e = 0; e < 4; ++e)
                    Rf[(16 * rt + quad * 4 + e) * RP16 + 16 * c + l15] =
                        (f16_t)fmaxf(h2a[rt][c][e] + b2[c], 0.f);
    }

    // ---- d3: out = h2 @ d3 + b3 (K=32) -> f32 out-stage in slab ----
    f16x8 a3[2];
#pragma unroll
    for (int rt = 0; rt < 2; ++rt)
        a3[rt] = *(const f16x8*)(Rf + (16 * rt + l15) * RP16 + quad * 8);
    float b3[4];
#pragma unroll
    for (int c = 0; c < 4; ++c) b3[c] = d3B[16 * c + l15];
#pragma unroll
    for (int c = 0; c < 4; ++c) {
        f16x8 bw = *(const f16x8*)(wsf + OFF_D3 + (16 * c + l15) * 32 + quad * 8);
#pragma unroll
        for (int rt = 0; rt < 2; ++rt) {
            f32x4 a = {};
            a = mfma1(a3[rt], bw, a);
#pragma unroll
            for (int e = 0; e < 4; ++e)
                Of[(16 * rt + quad * 4 + e) * OP32 + 16 * c + l15] = a[e] + b3[c];
        }
    }

    // ---- full-line store epilogue: 8 x 1KB contiguous wave-stores ----
    float* __restrict__ obase = out + (t0 + RB) * 64;
#pragma unroll
    for (int i = 0; i < 8; ++i) {
        const int r4 = i * 4 + (lane >> 4);
        f32x4 v = *(const f32x4*)(Of + r4 * OP32 + (lane & 15) * 4);
        *(f32x4*)(obase + i * 256 + lane * 4) = v;
    }
}

extern "C" void kernel_launch(void* const* d_in, const int* in_sizes, int n_in,
                              void* d_out, int out_size, void* d_ws, size_t ws_size,
                              hipStream_t stream) {
    (void)in_sizes; (void)n_in; (void)out_size; (void)ws_size;
    const float* kv_in = (const float*)d_in[0];
    const float* q_in  = (const float*)d_in[1];
    const float* keyW  = (const float*)d_in[2];
    const float* keyB  = (const float*)d_in[3];
    const float* valW  = (const float*)d_in[4];
    const float* valB  = (const float*)d_in[5];
    const float* TW    = (const float*)d_in[6];
    const float* TB    = (const float*)d_in[7];
    const float* d1W   = (const float*)d_in[8];
    const float* d1B   = (const float*)d_in[9];
    const float* d2W   = (const float*)d_in[10];
    const float* d2B   = (const float*)d_in[11];
    const float* d3W   = (const float*)d_in[12];
    const float* d3B   = (const float*)d_in[13];
    const float* scale = (const float*)d_in[14];
    f16_t* wsf = (f16_t*)d_ws;
    float* outp = (float*)d_out;

    prep_w<<<(WTOT + 255) / 256, 256, 0, stream>>>(keyW, valW, TW, TB, d1W, d2W, d3W, wsf);
    fused_mfma<<<NTOK / MT, TPB, 0, stream>>>(kv_in, q_in, keyB, valB,
                                              d1B, d2B, d3B, scale, wsf, outp);
}

// Round 10
// 159.078 us; speedup vs baseline: 1.1670x; 1.0889x over previous
//
#include <hip/hip_runtime.h>
#include <math.h>

typedef _Float16 f16_t;
typedef __attribute__((ext_vector_type(8))) _Float16 f16x8;
typedef __attribute__((ext_vector_type(4))) float f32x4;

#define NTOK 131072
#define MT   128      // tokens per block
#define TPB  256      // 4 waves; each wave owns 32 tokens; ZERO barriers
#define RP16 72       // relay pitch (f16)
#define OP32 68       // out-stage pitch (f32)
#define SLABB 8704

// ws layout (f16 elems)
#define OFF_KEY 0
#define OFF_VAL 4096
#define OFF_T   8192
#define OFF_D1  40960
#define OFF_D2  45056
#define OFF_D3  47104
#define WTOT    49152

__device__ __forceinline__ f32x4 mfma1(f16x8 a, f16x8 b, f32x4 c) {
    return __builtin_amdgcn_mfma_f32_16x16x32_f16(a, b, c, 0, 0, 0);
}

struct B2 { f16x8 b0, b1; };
__device__ __forceinline__ B2 loadB(const f16_t* __restrict__ bw, int c, int l15, int quad) {
    const f16_t* p = bw + (16 * c + l15) * 64 + quad * 8;
    B2 r; r.b0 = *(const f16x8*)p; r.b1 = *(const f16x8*)(p + 32); return r;
}

// one column-tile GEMM step on NAMED vars (no arrays anywhere)
#define GEMMC(bw, c, a00, a01, a10, a11, acc0, acc1) do {        \
    B2 Bf = loadB((bw), (c), l15, quad);                          \
    acc0 = mfma1(a01, Bf.b1, mfma1(a00, Bf.b0, acc0));            \
    acc1 = mfma1(a11, Bf.b1, mfma1(a10, Bf.b0, acc1));            \
} while (0)

// ---------------- prep: transpose all weights into ws as fp16 --------------
__global__ __launch_bounds__(256)
void prep_w(const float* __restrict__ keyW, const float* __restrict__ valW,
            const float* __restrict__ TW,   const float* __restrict__ TB,
            const float* __restrict__ d1W,  const float* __restrict__ d2W,
            const float* __restrict__ d3W,  f16_t* __restrict__ wsf)
{
    int idx = blockIdx.x * 256 + threadIdx.x;
    if (idx >= WTOT) return;
    float src;
    if (idx < OFF_VAL) {
        int r = idx - OFF_KEY, n = r >> 6, j = r & 63;
        src = keyW[j * 64 + n];
    } else if (idx < OFF_T) {
        int r = idx - OFF_VAL, n = r >> 6, j = r & 63;
        src = valW[j * 64 + n];
    } else if (idx < OFF_D1) {
        int r = idx - OFF_T, p = r >> 12, q = r & 4095;
        src = (p < 7) ? TW[p * 4096 + q] : TB[q];
    } else if (idx < OFF_D2) {
        int r = idx - OFF_D1, n = r >> 6, j = r & 63;
        src = d1W[j * 64 + n];
    } else if (idx < OFF_D3) {
        int r = idx - OFF_D2, n = r >> 6, j = r & 63;
        src = d2W[j * 32 + n];
    } else {
        int r = idx - OFF_D3, n = r >> 5, j = r & 31;
        src = d3W[j * 64 + n];
    }
    wsf[idx] = (f16_t)src;
}

// per-row-tile front: combined k|v GEMM + softmax + att + normalize + relay.
// All value parameters, all named locals — nothing can lower to scratch.
__device__ __forceinline__ void front_rt(
    f16_t* __restrict__ Rf, const f16_t* __restrict__ wsf,
    int l15, int quad, int rtb,
    f16x8 a0, f16x8 a1,
    f32x4 q0, f32x4 q1, f32x4 q2, f32x4 q3,
    f32x4 kbv, f32x4 vbv, float sc)
{
    const f16_t* wkv = wsf + OFF_KEY;
    f32x4 k0 = {}, k1 = {}, k2 = {}, k3 = {}, v0 = {}, v1 = {}, v2 = {}, v3 = {};
    { B2 B = loadB(wkv, 0, l15, quad); k0 = mfma1(a1, B.b1, mfma1(a0, B.b0, k0)); }
    { B2 B = loadB(wkv, 1, l15, quad); k1 = mfma1(a1, B.b1, mfma1(a0, B.b0, k1)); }
    { B2 B = loadB(wkv, 2, l15, quad); k2 = mfma1(a1, B.b1, mfma1(a0, B.b0, k2)); }
    { B2 B = loadB(wkv, 3, l15, quad); k3 = mfma1(a1, B.b1, mfma1(a0, B.b0, k3)); }
    { B2 B = loadB(wkv, 4, l15, quad); v0 = mfma1(a1, B.b1, mfma1(a0, B.b0, v0)); }
    { B2 B = loadB(wkv, 5, l15, quad); v1 = mfma1(a1, B.b1, mfma1(a0, B.b0, v1)); }
    { B2 B = loadB(wkv, 6, l15, quad); v2 = mfma1(a1, B.b1, mfma1(a0, B.b0, v2)); }
    { B2 B = loadB(wkv, 7, l15, quad); v3 = mfma1(a1, B.b1, mfma1(a0, B.b0, v3)); }

    f32x4 sv0 = (v0 + vbv[0]) * sc;
    f32x4 sv1 = (v1 + vbv[1]) * sc;
    f32x4 sv2 = (v2 + vbv[2]) * sc;
    f32x4 sv3 = (v3 + vbv[3]) * sc;

    f32x4 mx;
#pragma unroll
    for (int e = 0; e < 4; ++e)
        mx[e] = fmaxf(fmaxf(sv0[e], sv1[e]), fmaxf(sv2[e], sv3[e]));
#pragma unroll
    for (int m = 1; m < 16; m <<= 1)
#pragma unroll
        for (int e = 0; e < 4; ++e) mx[e] = fmaxf(mx[e], __shfl_xor(mx[e], m, 64));
#pragma unroll
    for (int e = 0; e < 4; ++e) {
        sv0[e] = __expf(sv0[e] - mx[e]);
        sv1[e] = __expf(sv1[e] - mx[e]);
        sv2[e] = __expf(sv2[e] - mx[e]);
        sv3[e] = __expf(sv3[e] - mx[e]);
    }
    f32x4 se = sv0 + sv1 + sv2 + sv3;
#pragma unroll
    for (int m = 1; m < 16; m <<= 1)
#pragma unroll
        for (int e = 0; e < 4; ++e) se[e] += __shfl_xor(se[e], m, 64);

    f32x4 at0 = q0 * (k0 + kbv[0]);
    f32x4 at1 = q1 * (k1 + kbv[1]);
    f32x4 at2 = q2 * (k2 + kbv[2]);
    f32x4 at3 = q3 * (k3 + kbv[3]);
    f32x4 nr = at0 * at0 + at1 * at1 + at2 * at2 + at3 * at3;
#pragma unroll
    for (int m = 1; m < 16; m <<= 1)
#pragma unroll
        for (int e = 0; e < 4; ++e) nr[e] += __shfl_xor(nr[e], m, 64);

    f32x4 fac;
#pragma unroll
    for (int e = 0; e < 4; ++e)
        fac[e] = 1.0f / (fmaxf(sqrtf(nr[e]), 1e-8f) * se[e]);

#pragma unroll
    for (int e = 0; e < 4; ++e) {
        f16_t* rr = Rf + (rtb + quad * 4 + e) * RP16 + l15;
        rr[0]  = (f16_t)(at0[e] * sv0[e] * fac[e]);
        rr[16] = (f16_t)(at1[e] * sv1[e] * fac[e]);
        rr[32] = (f16_t)(at2[e] * sv2[e] * fac[e]);
        rr[48] = (f16_t)(at3[e] * sv3[e] * fac[e]);
    }
}

// ------- main: R9 memory config, zero barriers, NO local arrays ------------
__global__ __launch_bounds__(TPB, 2)
void fused_mfma(const float* __restrict__ kv_in, const float* __restrict__ q_in,
                const float* __restrict__ keyB,  const float* __restrict__ valB,
                const float* __restrict__ d1B,   const float* __restrict__ d2B,
                const float* __restrict__ d3B,   const float* __restrict__ scale_p,
                const f16_t* __restrict__ wsf,   float* __restrict__ out)
{
    __shared__ __align__(16) unsigned char Slab[4][SLABB];   // 34816 B
    __shared__ __align__(16) float Qs[8][MT];                // 4096 B -> 38912 total

    const int tid  = threadIdx.x;
    const int wv   = tid >> 6, lane = tid & 63;
    const int quad = lane >> 4, l15 = lane & 15;
    const int RB   = wv * 32;
    const long t0  = (long)blockIdx.x * MT;

    f16_t* __restrict__ Rf = (f16_t*)Slab[wv];
    float* __restrict__ Of = (float*)Slab[wv];

    // ---- coalesced kv staging -> fp16 relay (wave-private) ----
    {
        const int r = lane >> 1, half = lane & 1;
        const float4* p4 = (const float4*)(kv_in + (t0 + RB + r) * 64 + half * 32);
        f16_t* dst = Rf + r * RP16 + half * 32;
#pragma unroll
        for (int b = 0; b < 4; ++b) {
            float4 f0 = p4[2 * b], f1 = p4[2 * b + 1];
            f16x8 h;
            h[0] = (f16_t)f0.x; h[1] = (f16_t)f0.y; h[2] = (f16_t)f0.z; h[3] = (f16_t)f0.w;
            h[4] = (f16_t)f1.x; h[5] = (f16_t)f1.y; h[6] = (f16_t)f1.z; h[7] = (f16_t)f1.w;
            *(f16x8*)(dst + 8 * b) = h;
        }
    }
    // ---- q' -> Qs (wave-private cols) ----
    if (lane < 32) {
        const float* qp = q_in + (t0 + RB + lane) * 7;
#pragma unroll
        for (int p = 0; p < 7; ++p) Qs[p][RB + lane] = qp[p];
        Qs[7][RB + lane] = 1.0f;
    }

    f32x4 kbv, vbv;
#pragma unroll
    for (int c = 0; c < 4; ++c) { kbv[c] = keyB[16 * c + l15]; vbv[c] = valB[16 * c + l15]; }
    const float sc = scale_p[0];

    // ---- A-fragments (named) ----
    f16x8 ah00 = *(const f16x8*)(Rf + l15 * RP16 + quad * 8);
    f16x8 ah01 = *(const f16x8*)(Rf + l15 * RP16 + 32 + quad * 8);
    f16x8 ah10 = *(const f16x8*)(Rf + (16 + l15) * RP16 + quad * 8);
    f16x8 ah11 = *(const f16x8*)(Rf + (16 + l15) * RP16 + 32 + quad * 8);

    // ---- T stage: q = sum_p q'_p * (KV @ T_p^T), named accumulators ----
    f32x4 q00 = {}, q01 = {}, q02 = {}, q03 = {};
    f32x4 q10 = {}, q11 = {}, q12 = {}, q13 = {};
#pragma unroll 1
    for (int p = 0; p < 8; ++p) {
        const f16_t* bt = wsf + OFF_T + p * 4096;
        f32x4 t00 = {}, t01 = {}, t02 = {}, t03 = {};
        f32x4 t10 = {}, t11 = {}, t12 = {}, t13 = {};
        GEMMC(bt, 0, ah00, ah01, ah10, ah11, t00, t10);
        GEMMC(bt, 1, ah00, ah01, ah10, ah11, t01, t11);
        GEMMC(bt, 2, ah00, ah01, ah10, ah11, t02, t12);
        GEMMC(bt, 3, ah00, ah01, ah10, ah11, t03, t13);
        f32x4 qp0 = *(const f32x4*)&Qs[p][RB + quad * 4];
        f32x4 qp1 = *(const f32x4*)&Qs[p][RB + 16 + quad * 4];
        q00 += qp0 * t00; q01 += qp0 * t01; q02 += qp0 * t02; q03 += qp0 * t03;
        q10 += qp1 * t10; q11 += qp1 * t11; q12 += qp1 * t12; q13 += qp1 * t13;
    }

    // ---- per row-tile front (k|v + elementwise + relay) ----
    front_rt(Rf, wsf, l15, quad, 0,  ah00, ah01, q00, q01, q02, q03, kbv, vbv, sc);
    front_rt(Rf, wsf, l15, quad, 16, ah10, ah11, q10, q11, q12, q13, kbv, vbv, sc);

    // ---- d1: h1 = relu(x @ d1 + b1) ----
    f16x8 xh00 = *(const f16x8*)(Rf + l15 * RP16 + quad * 8);
    f16x8 xh01 = *(const f16x8*)(Rf + l15 * RP16 + 32 + quad * 8);
    f16x8 xh10 = *(const f16x8*)(Rf + (16 + l15) * RP16 + quad * 8);
    f16x8 xh11 = *(const f16x8*)(Rf + (16 + l15) * RP16 + 32 + quad * 8);
    {
        const f16_t* wd1 = wsf + OFF_D1;
        f32x4 h00 = {}, h01 = {}, h02 = {}, h03 = {};
        f32x4 h10 = {}, h11 = {}, h12 = {}, h13 = {};
        GEMMC(wd1, 0, xh00, xh01, xh10, xh11, h00, h10);
        GEMMC(wd1, 1, xh00, xh01, xh10, xh11, h01, h11);
        GEMMC(wd1, 2, xh00, xh01, xh10, xh11, h02, h12);
        GEMMC(wd1, 3, xh00, xh01, xh10, xh11, h03, h13);
        f32x4 b1v;
#pragma unroll
        for (int c = 0; c < 4; ++c) b1v[c] = d1B[16 * c + l15];
#pragma unroll
        for (int e = 0; e < 4; ++e) {
            f16_t* r0 = Rf + (quad * 4 + e) * RP16 + l15;
            r0[0]  = (f16_t)fmaxf(h00[e] + b1v[0], 0.f);
            r0[16] = (f16_t)fmaxf(h01[e] + b1v[1], 0.f);
            r0[32] = (f16_t)fmaxf(h02[e] + b1v[2], 0.f);
            r0[48] = (f16_t)fmaxf(h03[e] + b1v[3], 0.f);
            f16_t* r1 = Rf + (16 + quad * 4 + e) * RP16 + l15;
            r1[0]  = (f16_t)fmaxf(h10[e] + b1v[0], 0.f);
            r1[16] = (f16_t)fmaxf(h11[e] + b1v[1], 0.f);
            r1[32] = (f16_t)fmaxf(h12[e] + b1v[2], 0.f);
            r1[48] = (f16_t)fmaxf(h13[e] + b1v[3], 0.f);
        }
    }

    // ---- d2: h2 = relu(h1 @ d2 + b2), 32 cols ----
    xh00 = *(const f16x8*)(Rf + l15 * RP16 + quad * 8);
    xh01 = *(const f16x8*)(Rf + l15 * RP16 + 32 + quad * 8);
    xh10 = *(const f16x8*)(Rf + (16 + l15) * RP16 + quad * 8);
    xh11 = *(const f16x8*)(Rf + (16 + l15) * RP16 + 32 + quad * 8);
    {
        const f16_t* wd2 = wsf + OFF_D2;
        f32x4 g00 = {}, g01 = {}, g10 = {}, g11 = {};
        GEMMC(wd2, 0, xh00, xh01, xh10, xh11, g00, g10);
        GEMMC(wd2, 1, xh00, xh01, xh10, xh11, g01, g11);
        float b20 = d2B[l15], b21 = d2B[16 + l15];
#pragma unroll
        for (int e = 0; e < 4; ++e) {
            f16_t* r0 = Rf + (quad * 4 + e) * RP16 + l15;
            r0[0]  = (f16_t)fmaxf(g00[e] + b20, 0.f);
            r0[16] = (f16_t)fmaxf(g01[e] + b21, 0.f);
            f16_t* r1 = Rf + (16 + quad * 4 + e) * RP16 + l15;
            r1[0]  = (f16_t)fmaxf(g10[e] + b20, 0.f);
            r1[16] = (f16_t)fmaxf(g11[e] + b21, 0.f);
        }
    }

    // ---- d3: out = h2 @ d3 + b3 (K=32) -> f32 out-stage in slab ----
    f16x8 a30 = *(const f16x8*)(Rf + l15 * RP16 + quad * 8);
    f16x8 a31 = *(const f16x8*)(Rf + (16 + l15) * RP16 + quad * 8);
    f32x4 b3v;
#pragma unroll
    for (int c = 0; c < 4; ++c) b3v[c] = d3B[16 * c + l15];
#pragma unroll
    for (int c = 0; c < 4; ++c) {
        f16x8 bw = *(const f16x8*)(wsf + OFF_D3 + (16 * c + l15) * 32 + quad * 8);
        f32x4 z = {};
        f32x4 o0 = mfma1(a30, bw, z);
        f32x4 o1 = mfma1(a31, bw, z);
#pragma unroll
        for (int e = 0; e < 4; ++e) {
            Of[(quad * 4 + e) * OP32 + 16 * c + l15]        = o0[e] + b3v[c];
            Of[(16 + quad * 4 + e) * OP32 + 16 * c + l15]   = o1[e] + b3v[c];
        }
    }

    // ---- full-line store epilogue: 8 x 1KB contiguous wave-stores ----
    float* __restrict__ obase = out + (t0 + RB) * 64;
#pragma unroll
    for (int i = 0; i < 8; ++i) {
        const int r4 = i * 4 + (lane >> 4);
        f32x4 v = *(const f32x4*)(Of + r4 * OP32 + (lane & 15) * 4);
        *(f32x4*)(obase + i * 256 + lane * 4) = v;
    }
}

extern "C" void kernel_launch(void* const* d_in, const int* in_sizes, int n_in,
                              void* d_out, int out_size, void* d_ws, size_t ws_size,
                              hipStream_t stream) {
    (void)in_sizes; (void)n_in; (void)out_size; (void)ws_size;
    const float* kv_in = (const float*)d_in[0];
    const float* q_in  = (const float*)d_in[1];
    const float* keyW  = (const float*)d_in[2];
    const float* keyB  = (const float*)d_in[3];
    const float* valW  = (const float*)d_in[4];
    const float* valB  = (const float*)d_in[5];
    const float* TW    = (const float*)d_in[6];
    const float* TB    = (const float*)d_in[7];
    const float* d1W   = (const float*)d_in[8];
    const float* d1B   = (const float*)d_in[9];
    const float* d2W   = (const float*)d_in[10];
    const float* d2B   = (const float*)d_in[11];
    const float* d3W   = (const float*)d_in[12];
    const float* d3B   = (const float*)d_in[13];
    const float* scale = (const float*)d_in[14];
    f16_t* wsf = (f16_t*)d_ws;
    float* outp = (float*)d_out;

    prep_w<<<(WTOT + 255) / 256, 256, 0, stream>>>(keyW, valW, TW, TB, d1W, d2W, d3W, wsf);
    fused_mfma<<<NTOK / MT, TPB, 0, stream>>>(kv_in, q_in, keyB, valB,
                                              d1B, d2B, d3B, scale, wsf, outp);
}